// Round 5
// baseline (4113.650 us; speedup 1.0000x reference)
//
#include <hip/hip_runtime.h>

// Problem dims
#define B_ 32
#define S_ 512
#define D_ 512
#define H_ 256

typedef float floatx4 __attribute__((ext_vector_type(4)));
typedef short short8v __attribute__((ext_vector_type(8)));
typedef unsigned short u16;
typedef unsigned int u32;
typedef unsigned long long u64;

#define WS_NEEDED 138544128ull

__device__ __forceinline__ u16 f2bf(float f) {
  u32 x = __float_as_uint(f);
  x += 0x7fffu + ((x >> 16) & 1u);   // RNE
  return (u16)(x >> 16);
}
__device__ __forceinline__ float bf2f(u16 h) {
  return __uint_as_float(((u32)h) << 16);
}
__device__ __forceinline__ float sigf(float x) {
  return 1.0f / (1.0f + __expf(-x));
}
__device__ __forceinline__ float tanh_f(float x) {
  float e = __expf(-2.0f * fabsf(x));
  float r = (1.0f - e) / (1.0f + e);
  return copysignf(r, x);
}

struct alignas(16) U16x8 { u16 v[8]; };

// ---------------- embedding -> X0 bf16, time-major (m = s*32+b, 512 feats) ----------------
__global__ void prep_k(const int* __restrict__ ids, const int* __restrict__ amask,
                       const float* __restrict__ emb, u16* __restrict__ X0) {
  int m = blockIdx.x;            // m = s*32 + b
  int lane = threadIdx.x;        // 64
  int s = m >> 5, b = m & 31;
  int id = ids[b * S_ + s];
  int mk = amask[b * S_ + s];
  const float4* src = (const float4*)(emb + (size_t)id * D_) + lane * 2;
  float4 v0 = src[0], v1 = src[1];
  if (!mk) { v0 = make_float4(0,0,0,0); v1 = make_float4(0,0,0,0); }
  U16x8 o;
  o.v[0]=f2bf(v0.x); o.v[1]=f2bf(v0.y); o.v[2]=f2bf(v0.z); o.v[3]=f2bf(v0.w);
  o.v[4]=f2bf(v1.x); o.v[5]=f2bf(v1.y); o.v[6]=f2bf(v1.z); o.v[7]=f2bf(v1.w);
  *(U16x8*)(X0 + (size_t)m * D_ + lane * 8) = o;
}

// ---------------- fp32 -> bf16 weight convert (w_ih, 2*2*1024*512 elems) ----------------
__global__ void conv_k(const float* __restrict__ w, u16* __restrict__ wbf, int n8) {
  int idx = blockIdx.x * blockDim.x + threadIdx.x;
  if (idx >= n8) return;
  const float4* s = (const float4*)w + (size_t)idx * 2;
  float4 v0 = s[0], v1 = s[1];
  U16x8 o;
  o.v[0]=f2bf(v0.x); o.v[1]=f2bf(v0.y); o.v[2]=f2bf(v0.z); o.v[3]=f2bf(v0.w);
  o.v[4]=f2bf(v1.x); o.v[5]=f2bf(v1.y); o.v[6]=f2bf(v1.z); o.v[7]=f2bf(v1.w);
  *(U16x8*)(wbf + (size_t)idx * 8) = o;
}

// ---------------- zero sync flags / loss ----------------
// flags: 8 groups x 32 ints (128B per group: [batch(8)][slice(4)])
__global__ void zero_k(int* __restrict__ flg, float* __restrict__ loss) {
  int idx = threadIdx.x;
  if (idx < 256) flg[idx] = 0;
  if (idx == 0) *loss = 0.f;
}

// ---------------- bf16 MFMA GEMM: G[m][n] = A[m][:] . W[n][:] + bih[n] + bhh[n] ----------------
__global__ void gemm_k(const u16* __restrict__ A, const u16* __restrict__ W,
                       const float* __restrict__ bih, const float* __restrict__ bhh,
                       u16* __restrict__ G) {
  __shared__ short Asm[64 * 40];
  __shared__ short Bsm[64 * 40];
  const int tid = threadIdx.x;
  const int m0 = blockIdx.x * 64, n0 = blockIdx.y * 64;
  const int wid = tid >> 6, lane = tid & 63;
  const int quad = lane >> 4, lr = lane & 15;
  const int wm = (wid >> 1) * 32, wn = (wid & 1) * 32;
  const int lrow = tid >> 2, lk = (tid & 3) * 8;
  floatx4 acc00 = {0,0,0,0}, acc01 = {0,0,0,0}, acc10 = {0,0,0,0}, acc11 = {0,0,0,0};
  for (int kt = 0; kt < 16; ++kt) {
    const int k0 = kt * 32;
    uint4 av = *(const uint4*)(A + (size_t)(m0 + lrow) * 512 + k0 + lk);
    uint4 bv = *(const uint4*)(W + (size_t)(n0 + lrow) * 512 + k0 + lk);
    __syncthreads();
    *(uint4*)&Asm[lrow * 40 + lk] = av;
    *(uint4*)&Bsm[lrow * 40 + lk] = bv;
    __syncthreads();
    short8v a0 = *(const short8v*)&Asm[(wm + lr) * 40 + quad * 8];
    short8v a1 = *(const short8v*)&Asm[(wm + 16 + lr) * 40 + quad * 8];
    short8v b0 = *(const short8v*)&Bsm[(wn + lr) * 40 + quad * 8];
    short8v b1 = *(const short8v*)&Bsm[(wn + 16 + lr) * 40 + quad * 8];
    acc00 = __builtin_amdgcn_mfma_f32_16x16x32_bf16(a0, b0, acc00, 0, 0, 0);
    acc01 = __builtin_amdgcn_mfma_f32_16x16x32_bf16(a0, b1, acc01, 0, 0, 0);
    acc10 = __builtin_amdgcn_mfma_f32_16x16x32_bf16(a1, b0, acc10, 0, 0, 0);
    acc11 = __builtin_amdgcn_mfma_f32_16x16x32_bf16(a1, b1, acc11, 0, 0, 0);
  }
  #pragma unroll
  for (int j = 0; j < 2; ++j) {
    const int n = n0 + wn + j * 16 + lr;
    const float bias = bih[n] + bhh[n];
    #pragma unroll
    for (int i = 0; i < 2; ++i) {
      const int mb = m0 + wm + i * 16 + quad * 4;
      floatx4 av = (i == 0) ? (j == 0 ? acc00 : acc01) : (j == 0 ? acc10 : acc11);
      #pragma unroll
      for (int rr = 0; rr < 4; ++rr) {
        G[(size_t)(mb + rr) * 2048 + n] = f2bf(av[rr] + bias);
      }
    }
  }
}

// ---------------- LSTM recurrence via MFMA, weights resident in VGPRs ----------------
// grid 32 = dir(2) x slice(4) x bg(4); 512 threads (8 waves).
// Per-step sync (NO wg-wide rendezvous on the signal path):
//   producer wave w: h-store (relaxed agent) -> per-wave s_waitcnt vmcnt(0)
//   -> lane0 stores flags[w*4+slice] = st+1 -> X store (deferred).
//   consumer wave w: polls only its 4 producer flags (batch w, slices 0..3).
// G loads issued BEFORE the poll so the B1 vmcnt drain never exposes their latency.
__launch_bounds__(512, 1)
__global__ void rec_k(const u16* __restrict__ G, const float* __restrict__ whh_l,
                      u32* __restrict__ Hbuf, int* __restrict__ flg,
                      u16* __restrict__ Xbf, float* __restrict__ Xf) {
  __shared__ u16 hhi_lds[16][264];   // [batch(8 real+8 zero)][k=256 pad 264]
  __shared__ u16 hlo_lds[16][264];
  __shared__ float part[4 * 64 * 17]; // [type][jj][b pad17]
  __shared__ float clds[512];         // c state: [b][jj] = clds[tid]

  const int tid = threadIdx.x;
  const int dir = blockIdx.x >> 4;
  const int slice = (blockIdx.x >> 2) & 3;
  const int bg = blockIdx.x & 3;
  const int s64 = slice * 64;
  const int w = tid >> 6;
  const int lane = tid & 63;
  const int q = lane >> 4;      // quad
  const int lr = lane & 15;
  const int type = w >> 1;      // gate type for MFMA phase
  const int jjb = (w & 1) * 32; // hidden base within 64-slice

  const float* whh = whh_l + (size_t)dir * (1024 * 256);

  // ---- one-time: preload Whh slice into VGPR A-fragments (hi + lo residual) ----
  short8v Ahi[2][8], Alo[2][8];
  #pragma unroll
  for (int ti = 0; ti < 2; ++ti) {
    const float* wrow = whh + (size_t)(type * 256 + s64 + jjb + ti * 16 + lr) * 256;
    #pragma unroll
    for (int ks = 0; ks < 8; ++ks) {
      const float* pk = wrow + ks * 32 + q * 8;
      short8v hi, lo;
      #pragma unroll
      for (int j = 0; j < 8; ++j) {
        float v = pk[j];
        u16 hb = f2bf(v);
        hi[j] = (short)hb;
        lo[j] = (short)f2bf(v - bf2f(hb));
      }
      Ahi[ti][ks] = hi; Alo[ti][ks] = lo;
    }
  }
  for (int i = tid; i < 16 * 264; i += 512) {
    ((u16*)hhi_lds)[i] = 0; ((u16*)hlo_lds)[i] = 0;
  }
  clds[tid] = 0.f;

  int* flags = flg + (dir * 4 + bg) * 32;           // 128B line: [batch][slice]
  u32* hb = Hbuf + (size_t)(dir * 4 + bg) * 4096;   // 2 parity * 2048 u32
  const int bu = w;       // updater: batch in group (0..7)
  const int ju = lane;    // updater: hidden in slice (0..63)
  __syncthreads();

  for (int st = 0; st < 512; ++st) {
    const int t = dir ? (511 - st) : st;
    const int par = st & 1;
    // G loads FIRST: overlap with poll + h-load latency (address depends only on st)
    const u16* gp = G + (size_t)(t * 32 + bg * 8 + bu) * 2048 + dir * 1024 + s64 + ju;
    u16 gv0 = gp[0], gv1 = gp[256], gv2 = gp[512], gv3 = gp[768];
    if (st > 0) {
      // per-wave poll: wave w needs batch-w producers of all 4 slices
      const u32 target = (u32)st;
      int spin = 0;
      for (;;) {
        u32 fv = target;
        if (lane < 4)
          fv = __hip_atomic_load((const u32*)&flags[w * 4 + lane],
                                 __ATOMIC_RELAXED, __HIP_MEMORY_SCOPE_AGENT);
        u64 ok = __ballot(fv >= target);
        if (ok == ~0ull) break;
        if (++spin > (1 << 20)) break;   // hang-avoidance only
      }
      asm volatile("" ::: "memory");     // no hoisting h loads above the poll
    }
    // h_prev: packed u32 loads -> unpack -> LDS (B-operand layout [b][k])
    if (st > 0) {
      const u64* src = (const u64*)(hb + par * 2048);
      u64 p0 = __hip_atomic_load(src + 2 * tid,     __ATOMIC_RELAXED, __HIP_MEMORY_SCOPE_AGENT);
      u64 p1 = __hip_atomic_load(src + 2 * tid + 1, __ATOMIC_RELAXED, __HIP_MEMORY_SCOPE_AGENT);
      u32 c0 = (u32)p0, c1 = (u32)(p0 >> 32), c2 = (u32)p1, c3 = (u32)(p1 >> 32);
      const int b = tid >> 6, k4 = (tid & 63) * 4;
      u64 hiq = (u64)(c0 >> 16) | ((u64)(c1 >> 16) << 16)
              | ((u64)(c2 >> 16) << 32) | ((u64)(c3 >> 16) << 48);
      u64 loq = (u64)(c0 & 0xffffu) | ((u64)(c1 & 0xffffu) << 16)
              | ((u64)(c2 & 0xffffu) << 32) | ((u64)(c3 & 0xffffu) << 48);
      *(u64*)&hhi_lds[b][k4] = hiq;
      *(u64*)&hlo_lds[b][k4] = loq;
    }
    __syncthreads();   // B1
    // MFMA phase: out[row][b] = W[row][:] . h[:][b]  (3-term hi/lo split)
    floatx4 acc0 = {0,0,0,0}, acc1 = {0,0,0,0};
    #pragma unroll
    for (int ks = 0; ks < 8; ++ks) {
      short8v bhi = *(const short8v*)&hhi_lds[lr][ks * 32 + q * 8];
      short8v blo = *(const short8v*)&hlo_lds[lr][ks * 32 + q * 8];
      acc0 = __builtin_amdgcn_mfma_f32_16x16x32_bf16(Ahi[0][ks], bhi, acc0, 0, 0, 0);
      acc1 = __builtin_amdgcn_mfma_f32_16x16x32_bf16(Ahi[1][ks], bhi, acc1, 0, 0, 0);
      acc0 = __builtin_amdgcn_mfma_f32_16x16x32_bf16(Alo[0][ks], bhi, acc0, 0, 0, 0);
      acc1 = __builtin_amdgcn_mfma_f32_16x16x32_bf16(Alo[1][ks], bhi, acc1, 0, 0, 0);
      acc0 = __builtin_amdgcn_mfma_f32_16x16x32_bf16(Ahi[0][ks], blo, acc0, 0, 0, 0);
      acc1 = __builtin_amdgcn_mfma_f32_16x16x32_bf16(Ahi[1][ks], blo, acc1, 0, 0, 0);
    }
    // C layout: col(b)=lane&15, row(jj)=quad*4+reg
    #pragma unroll
    for (int reg = 0; reg < 4; ++reg) {
      part[(type * 64 + jjb +      q * 4 + reg) * 17 + lr] = acc0[reg];
      part[(type * 64 + jjb + 16 + q * 4 + reg) * 17 + lr] = acc1[reg];
    }
    __syncthreads();   // B2
    // updater phase: all 512 threads, one (b,jj) each
    float si = bf2f(gv0) + part[(0 * 64 + ju) * 17 + bu];
    float sf = bf2f(gv1) + part[(1 * 64 + ju) * 17 + bu];
    float sg = bf2f(gv2) + part[(2 * 64 + ju) * 17 + bu];
    float so = bf2f(gv3) + part[(3 * 64 + ju) * 17 + bu];
    float cold = clds[tid];
    float ig = sigf(si), fg = sigf(sf), gg = tanh_f(sg), og = sigf(so);
    float cn = fg * cold + ig * gg;
    float hn = og * tanh_f(cn);
    clds[tid] = cn;
    u16 hhi = f2bf(hn);
    u16 hlo = f2bf(hn - bf2f(hhi));
    u32 hv = ((u32)hhi << 16) | hlo;
    __hip_atomic_store(hb + (par ^ 1) * 2048 + bu * 256 + s64 + ju, hv,
                       __ATOMIC_RELAXED, __HIP_MEMORY_SCOPE_AGENT);
    // per-wave drain of this wave's h stores, then per-wave flag (NO barrier)
    asm volatile("s_waitcnt vmcnt(0)" ::: "memory");
    if (lane == 0)
      __hip_atomic_store((u32*)&flags[bu * 4 + slice], (u32)(st + 1),
                         __ATOMIC_RELAXED, __HIP_MEMORY_SCOPE_AGENT);
    // X output deferred past the flag store (off the critical path)
    const size_t oidx = ((size_t)t * 32 + (bg * 8 + bu)) * 512 + dir * 256 + s64 + ju;
    if (Xbf) Xbf[oidx] = hhi;
    else     Xf[oidx] = hn;
  }
}

// ---------------- LayerNorm + classifier head; logits -> d_out+1 ----------------
__global__ void head_k(const float* __restrict__ X2, const float* __restrict__ gamma,
                       const float* __restrict__ beta, const float* __restrict__ cw,
                       const float* __restrict__ cb, float* __restrict__ out) {
  __shared__ float red[9][64];
  const int m = blockIdx.x, lane = threadIdx.x;
  const int s = m >> 5, b = m & 31;
  const float4* xp = (const float4*)(X2 + (size_t)m * 512) + lane * 2;
  float4 x0 = xp[0], x1 = xp[1];
  float sm = x0.x + x0.y + x0.z + x0.w + x1.x + x1.y + x1.z + x1.w;
  float sq = x0.x*x0.x + x0.y*x0.y + x0.z*x0.z + x0.w*x0.w
           + x1.x*x1.x + x1.y*x1.y + x1.z*x1.z + x1.w*x1.w;
  #pragma unroll
  for (int off = 32; off > 0; off >>= 1) {
    sm += __shfl_xor(sm, off, 64);
    sq += __shfl_xor(sq, off, 64);
  }
  const float mu = sm * (1.0f / 512.0f);
  const float var = sq * (1.0f / 512.0f) - mu * mu;
  const float rs = rsqrtf(var + 1e-5f);
  const float4* gp = (const float4*)gamma + lane * 2;
  const float4* bp = (const float4*)beta + lane * 2;
  float4 g0 = gp[0], g1 = gp[1], be0 = bp[0], be1 = bp[1];
  float nv[8];
  nv[0] = (x0.x - mu) * rs * g0.x + be0.x;
  nv[1] = (x0.y - mu) * rs * g0.y + be0.y;
  nv[2] = (x0.z - mu) * rs * g0.z + be0.z;
  nv[3] = (x0.w - mu) * rs * g0.w + be0.w;
  nv[4] = (x1.x - mu) * rs * g1.x + be1.x;
  nv[5] = (x1.y - mu) * rs * g1.y + be1.y;
  nv[6] = (x1.z - mu) * rs * g1.z + be1.z;
  nv[7] = (x1.w - mu) * rs * g1.w + be1.w;
  #pragma unroll
  for (int c = 0; c < 9; ++c) {
    const float4* wp = (const float4*)(cw + (size_t)c * 512) + lane * 2;
    float4 w0 = wp[0], w1 = wp[1];
    red[c][lane] = nv[0]*w0.x + nv[1]*w0.y + nv[2]*w0.z + nv[3]*w0.w
                 + nv[4]*w1.x + nv[5]*w1.y + nv[6]*w1.z + nv[7]*w1.w;
  }
  __syncthreads();
  if (lane < 9) {
    float t = 0.f;
    for (int i = 0; i < 64; ++i) t += red[lane][i];
    out[1 + ((size_t)b * 512 + s) * 9 + lane] = t + cb[lane];
  }
}

// ---------------- CRF NLL: one wave per batch element ----------------
__global__ void crf_k(const float* __restrict__ logits, const int* __restrict__ labels,
                      const int* __restrict__ lens, const float* __restrict__ tr,
                      float* __restrict__ loss) {
  const int b = blockIdx.x, lane = threadIdx.x;
  const int len = lens[b];
  float trj[9];
  #pragma unroll
  for (int i = 0; i < 9; ++i) trj[i] = 0.f;
  if (lane < 9) {
    #pragma unroll
    for (int i = 0; i < 9; ++i) trj[i] = tr[i * 11 + lane];
  }
  float alpha = -1e30f;
  if (lane < 9) alpha = tr[9 * 11 + lane] + logits[(size_t)b * 512 * 9 + lane];
  for (int t = 1; t < len; ++t) {
    float e = (lane < 9) ? logits[((size_t)b * 512 + t) * 9 + lane] : 0.f;
    float v[9];
    float mx = -1e30f;
    #pragma unroll
    for (int i = 0; i < 9; ++i) {
      v[i] = __shfl(alpha, i, 64) + trj[i];
      mx = fmaxf(mx, v[i]);
    }
    float ss = 0.f;
    #pragma unroll
    for (int i = 0; i < 9; ++i) ss += __expf(v[i] - mx);
    float na = mx + __logf(ss) + e;
    if (lane < 9) alpha = na;
  }
  float fin = (lane < 9) ? alpha + tr[lane * 11 + 10] : -1e30f;
  float mx = fin;
  #pragma unroll
  for (int off = 8; off > 0; off >>= 1) mx = fmaxf(mx, __shfl_xor(mx, off, 64));
  float es = (lane < 9) ? __expf(fin - mx) : 0.f;
  #pragma unroll
  for (int off = 8; off > 0; off >>= 1) es += __shfl_xor(es, off, 64);
  const float logZ = mx + __logf(es);
  float emit = 0.f, ts = 0.f;
  for (int t = lane; t < len; t += 64) {
    int y = labels[b * 512 + t];
    emit += logits[((size_t)b * 512 + t) * 9 + y];
  }
  for (int t = 1 + lane; t < len; t += 64) {
    int y0 = labels[b * 512 + t - 1], y1 = labels[b * 512 + t];
    ts += tr[y0 * 11 + y1];
  }
  #pragma unroll
  for (int off = 32; off > 0; off >>= 1) {
    emit += __shfl_xor(emit, off, 64);
    ts += __shfl_xor(ts, off, 64);
  }
  if (lane == 0) {
    int y0 = labels[b * 512], yl = labels[b * 512 + len - 1];
    float gold = emit + ts + tr[9 * 11 + y0] + tr[yl * 11 + 10];
    atomicAdd(loss, (logZ - gold) * (1.0f / 32.0f));
  }
}

extern "C" void kernel_launch(void* const* d_in, const int* in_sizes, int n_in,
                              void* d_out, int out_size, void* d_ws, size_t ws_size,
                              hipStream_t stream) {
  const int* ids = (const int*)d_in[0];
  const int* amask = (const int*)d_in[1];
  const int* lens = (const int*)d_in[2];
  const int* labels = (const int*)d_in[3];
  const float* emb = (const float*)d_in[4];
  const float* w_ih = (const float*)d_in[5];
  const float* w_hh = (const float*)d_in[6];
  const float* b_ih = (const float*)d_in[7];
  const float* b_hh = (const float*)d_in[8];
  const float* gamma = (const float*)d_in[9];
  const float* beta = (const float*)d_in[10];
  const float* cw = (const float*)d_in[11];
  const float* cb = (const float*)d_in[12];
  const float* tr = (const float*)d_in[13];
  (void)in_sizes; (void)n_in; (void)out_size;

  if (ws_size < WS_NEEDED) return;  // workspace too small -> clean failure

  char* p = (char*)d_ws;
  u16* X0 = (u16*)p;      p += (size_t)16384 * 512 * 2;        // 16.78 MB
  u16* Wbf = (u16*)p;     p += (size_t)2 * 2 * 1024 * 512 * 2; // 4.19 MB
  u16* G = (u16*)p;       p += (size_t)16384 * 2048 * 2;       // 67.1 MB
  u16* X1 = (u16*)p;      p += (size_t)16384 * 512 * 2;        // 16.78 MB
  float* X2 = (float*)p;  p += (size_t)16384 * 512 * 4;        // 33.55 MB
  u32* Hb = (u32*)p;      p += (size_t)32768 * 4;              // 128 KB
  int* flg = (int*)p;     p += 1024;                           // 8 groups x 128B
  float* out = (float*)d_out;

  prep_k<<<16384, 64, 0, stream>>>(ids, amask, emb, X0);
  conv_k<<<1024, 256, 0, stream>>>(w_ih, Wbf, 262144);
  zero_k<<<1, 256, 0, stream>>>(flg, out);
  // Layer 0
  gemm_k<<<dim3(256, 32), 256, 0, stream>>>(X0, Wbf, b_ih, b_hh, G);
  rec_k<<<32, 512, 0, stream>>>(G, w_hh, Hb, flg, X1, nullptr);
  zero_k<<<1, 256, 0, stream>>>(flg, out);
  // Layer 1
  gemm_k<<<dim3(256, 32), 256, 0, stream>>>(X1, Wbf + 2 * 1024 * 512,
                                            b_ih + 2048, b_hh + 2048, G);
  rec_k<<<32, 512, 0, stream>>>(G, w_hh + 2 * 1024 * 256, Hb, flg,
                                nullptr, X2);
  // Head + CRF
  head_k<<<16384, 64, 0, stream>>>(X2, gamma, beta, cw, cb, out);
  crf_k<<<32, 64, 0, stream>>>(out + 1, labels, lens, tr, out);
}

// Round 6
// 3420.937 us; speedup vs baseline: 1.2025x; 1.2025x over previous
//
#include <hip/hip_runtime.h>

// Problem dims
#define B_ 32
#define S_ 512
#define D_ 512
#define H_ 256

typedef float floatx4 __attribute__((ext_vector_type(4)));
typedef short short8v __attribute__((ext_vector_type(8)));
typedef unsigned short u16;
typedef unsigned int u32;
typedef unsigned long long u64;

#define WS_NEEDED 138575872ull

__device__ __forceinline__ u16 f2bf(float f) {
  u32 x = __float_as_uint(f);
  x += 0x7fffu + ((x >> 16) & 1u);   // RNE
  return (u16)(x >> 16);
}
__device__ __forceinline__ float bf2f(u16 h) {
  return __uint_as_float(((u32)h) << 16);
}
__device__ __forceinline__ float sigf(float x) {
  return 1.0f / (1.0f + __expf(-x));
}
__device__ __forceinline__ float tanh_f(float x) {
  float e = __expf(-2.0f * fabsf(x));
  float r = (1.0f - e) / (1.0f + e);
  return copysignf(r, x);
}

struct alignas(16) U16x8 { u16 v[8]; };

// ---------------- embedding -> X0 bf16, time-major (m = s*32+b, 512 feats) ----------------
__global__ void prep_k(const int* __restrict__ ids, const int* __restrict__ amask,
                       const float* __restrict__ emb, u16* __restrict__ X0) {
  int m = blockIdx.x;            // m = s*32 + b
  int lane = threadIdx.x;        // 64
  int s = m >> 5, b = m & 31;
  int id = ids[b * S_ + s];
  int mk = amask[b * S_ + s];
  const float4* src = (const float4*)(emb + (size_t)id * D_) + lane * 2;
  float4 v0 = src[0], v1 = src[1];
  if (!mk) { v0 = make_float4(0,0,0,0); v1 = make_float4(0,0,0,0); }
  U16x8 o;
  o.v[0]=f2bf(v0.x); o.v[1]=f2bf(v0.y); o.v[2]=f2bf(v0.z); o.v[3]=f2bf(v0.w);
  o.v[4]=f2bf(v1.x); o.v[5]=f2bf(v1.y); o.v[6]=f2bf(v1.z); o.v[7]=f2bf(v1.w);
  *(U16x8*)(X0 + (size_t)m * D_ + lane * 8) = o;
}

// ---------------- fp32 -> bf16 weight convert (w_ih, 2*2*1024*512 elems) ----------------
__global__ void conv_k(const float* __restrict__ w, u16* __restrict__ wbf, int n8) {
  int idx = blockIdx.x * blockDim.x + threadIdx.x;
  if (idx >= n8) return;
  const float4* s = (const float4*)w + (size_t)idx * 2;
  float4 v0 = s[0], v1 = s[1];
  U16x8 o;
  o.v[0]=f2bf(v0.x); o.v[1]=f2bf(v0.y); o.v[2]=f2bf(v0.z); o.v[3]=f2bf(v0.w);
  o.v[4]=f2bf(v1.x); o.v[5]=f2bf(v1.y); o.v[6]=f2bf(v1.z); o.v[7]=f2bf(v1.w);
  *(U16x8*)(wbf + (size_t)idx * 8) = o;
}

// ---------------- zero sync flags / loss ----------------
// flags: 8 groups x 8 batches x 4 slices x 32 ints (one 128B line per producer)
__global__ void zero_k(int* __restrict__ flg, float* __restrict__ loss) {
  int idx = blockIdx.x * 512 + threadIdx.x;
  if (idx < 8192) flg[idx] = 0;
  if (idx == 0) *loss = 0.f;
}

// ---------------- bf16 MFMA GEMM: G[m][n] = A[m][:] . W[n][:] + bih[n] + bhh[n] ----------------
__global__ void gemm_k(const u16* __restrict__ A, const u16* __restrict__ W,
                       const float* __restrict__ bih, const float* __restrict__ bhh,
                       u16* __restrict__ G) {
  __shared__ short Asm[64 * 40];
  __shared__ short Bsm[64 * 40];
  const int tid = threadIdx.x;
  const int m0 = blockIdx.x * 64, n0 = blockIdx.y * 64;
  const int wid = tid >> 6, lane = tid & 63;
  const int quad = lane >> 4, lr = lane & 15;
  const int wm = (wid >> 1) * 32, wn = (wid & 1) * 32;
  const int lrow = tid >> 2, lk = (tid & 3) * 8;
  floatx4 acc00 = {0,0,0,0}, acc01 = {0,0,0,0}, acc10 = {0,0,0,0}, acc11 = {0,0,0,0};
  for (int kt = 0; kt < 16; ++kt) {
    const int k0 = kt * 32;
    uint4 av = *(const uint4*)(A + (size_t)(m0 + lrow) * 512 + k0 + lk);
    uint4 bv = *(const uint4*)(W + (size_t)(n0 + lrow) * 512 + k0 + lk);
    __syncthreads();
    *(uint4*)&Asm[lrow * 40 + lk] = av;
    *(uint4*)&Bsm[lrow * 40 + lk] = bv;
    __syncthreads();
    short8v a0 = *(const short8v*)&Asm[(wm + lr) * 40 + quad * 8];
    short8v a1 = *(const short8v*)&Asm[(wm + 16 + lr) * 40 + quad * 8];
    short8v b0 = *(const short8v*)&Bsm[(wn + lr) * 40 + quad * 8];
    short8v b1 = *(const short8v*)&Bsm[(wn + 16 + lr) * 40 + quad * 8];
    acc00 = __builtin_amdgcn_mfma_f32_16x16x32_bf16(a0, b0, acc00, 0, 0, 0);
    acc01 = __builtin_amdgcn_mfma_f32_16x16x32_bf16(a0, b1, acc01, 0, 0, 0);
    acc10 = __builtin_amdgcn_mfma_f32_16x16x32_bf16(a1, b0, acc10, 0, 0, 0);
    acc11 = __builtin_amdgcn_mfma_f32_16x16x32_bf16(a1, b1, acc11, 0, 0, 0);
  }
  #pragma unroll
  for (int j = 0; j < 2; ++j) {
    const int n = n0 + wn + j * 16 + lr;
    const float bias = bih[n] + bhh[n];
    #pragma unroll
    for (int i = 0; i < 2; ++i) {
      const int mb = m0 + wm + i * 16 + quad * 4;
      floatx4 av = (i == 0) ? (j == 0 ? acc00 : acc01) : (j == 0 ? acc10 : acc11);
      #pragma unroll
      for (int rr = 0; rr < 4; ++rr) {
        G[(size_t)(mb + rr) * 2048 + n] = f2bf(av[rr] + bias);
      }
    }
  }
}

// ---------------- LSTM recurrence via MFMA, weights resident in VGPRs ----------------
// grid 32 = dir(2) x slice(4) x bg(4); 512 threads (8 waves).
// Sync per step: producer wave bu stores h+X, per-wave s_waitcnt vmcnt(0),
// lane0 stores its OWN 128B flag line (single writer per line, NO RMW, no
// line sharing between writers). Consumer wave w polls its 4 producer lines
// with one 4-lane load; no outstanding vmem during the poll.
// G gate-preactivations software-pipelined one step ahead (issued after B1,
// drained by B2's mandatory vmcnt(0), hidden under MFMA).
__launch_bounds__(512, 1)
__global__ void rec_k(const u16* __restrict__ G, const float* __restrict__ whh_l,
                      u32* __restrict__ Hbuf, int* __restrict__ flg,
                      u16* __restrict__ Xbf, float* __restrict__ Xf) {
  __shared__ u16 hhi_lds[16][264];   // [batch(8 real+8 zero)][k=256 pad 264]
  __shared__ u16 hlo_lds[16][264];
  __shared__ float part[4 * 64 * 17]; // [type][jj][b pad17]
  __shared__ float clds[512];         // c state: [b][jj] = clds[tid]

  const int tid = threadIdx.x;
  const int dir = blockIdx.x >> 4;
  const int slice = (blockIdx.x >> 2) & 3;
  const int bg = blockIdx.x & 3;
  const int s64 = slice * 64;
  const int w = tid >> 6;
  const int lane = tid & 63;
  const int q = lane >> 4;      // quad
  const int lr = lane & 15;
  const int type = w >> 1;      // gate type for MFMA phase
  const int jjb = (w & 1) * 32; // hidden base within 64-slice

  const float* whh = whh_l + (size_t)dir * (1024 * 256);

  // ---- one-time: preload Whh slice into VGPR A-fragments (hi + lo residual) ----
  short8v Ahi[2][8], Alo[2][8];
  #pragma unroll
  for (int ti = 0; ti < 2; ++ti) {
    const float* wrow = whh + (size_t)(type * 256 + s64 + jjb + ti * 16 + lr) * 256;
    #pragma unroll
    for (int ks = 0; ks < 8; ++ks) {
      const float* pk = wrow + ks * 32 + q * 8;
      short8v hi, lo;
      #pragma unroll
      for (int j = 0; j < 8; ++j) {
        float v = pk[j];
        u16 hb = f2bf(v);
        hi[j] = (short)hb;
        lo[j] = (short)f2bf(v - bf2f(hb));
      }
      Ahi[ti][ks] = hi; Alo[ti][ks] = lo;
    }
  }
  for (int i = tid; i < 16 * 264; i += 512) {
    ((u16*)hhi_lds)[i] = 0; ((u16*)hlo_lds)[i] = 0;
  }
  clds[tid] = 0.f;

  // flag lines: group base + ((batch*4 + slice) * 32) ints -> 128B per producer
  int* flags = flg + (dir * 4 + bg) * 1024;
  u32* hb = Hbuf + (size_t)(dir * 4 + bg) * 4096;   // 2 parity * 2048 u32
  const int bu = w;       // updater: batch in group (0..7)
  const int ju = lane;    // updater: hidden in slice (0..63)

  // preamble: load G[st=0]
  u16 gn0, gn1, gn2, gn3;
  {
    const int t0 = dir ? 511 : 0;
    const u16* gp = G + (size_t)(t0 * 32 + bg * 8 + bu) * 2048 + dir * 1024 + s64 + ju;
    gn0 = gp[0]; gn1 = gp[256]; gn2 = gp[512]; gn3 = gp[768];
  }
  __syncthreads();

  for (int st = 0; st < 512; ++st) {
    const int t = dir ? (511 - st) : st;
    const int par = st & 1;
    // current step's gates (prefetched last iteration, already drained)
    const u16 gv0 = gn0, gv1 = gn1, gv2 = gn2, gv3 = gn3;
    if (st > 0) {
      // per-wave poll: wave w needs batch-w producers of all 4 slices.
      // No outstanding vmem here -> each check is a bare flag-line load.
      const u32 target = (u32)st;
      int spin = 0;
      for (;;) {
        u32 fv = target;
        if (lane < 4)
          fv = __hip_atomic_load((const u32*)&flags[(w * 4 + lane) * 32],
                                 __ATOMIC_RELAXED, __HIP_MEMORY_SCOPE_AGENT);
        u64 ok = __ballot(fv >= target);
        if (ok == ~0ull) break;
        if (++spin > (1 << 20)) break;   // hang-avoidance only
      }
      asm volatile("" ::: "memory");     // no hoisting h loads above the poll
    }
    // h_prev: packed u32 loads -> unpack -> LDS (B-operand layout [b][k])
    if (st > 0) {
      const u64* src = (const u64*)(hb + par * 2048);
      u64 p0 = __hip_atomic_load(src + 2 * tid,     __ATOMIC_RELAXED, __HIP_MEMORY_SCOPE_AGENT);
      u64 p1 = __hip_atomic_load(src + 2 * tid + 1, __ATOMIC_RELAXED, __HIP_MEMORY_SCOPE_AGENT);
      u32 c0 = (u32)p0, c1 = (u32)(p0 >> 32), c2 = (u32)p1, c3 = (u32)(p1 >> 32);
      const int b = tid >> 6, k4 = (tid & 63) * 4;
      u64 hiq = (u64)(c0 >> 16) | ((u64)(c1 >> 16) << 16)
              | ((u64)(c2 >> 16) << 32) | ((u64)(c3 >> 16) << 48);
      u64 loq = (u64)(c0 & 0xffffu) | ((u64)(c1 & 0xffffu) << 16)
              | ((u64)(c2 & 0xffffu) << 32) | ((u64)(c3 & 0xffffu) << 48);
      *(u64*)&hhi_lds[b][k4] = hiq;
      *(u64*)&hlo_lds[b][k4] = loq;
    }
    __syncthreads();   // B1 (drains h loads; also preamble G on st=0)
    // prefetch NEXT step's G: hidden under MFMA, drained by B2's vmcnt(0)
    {
      const int stn = (st < 511) ? st + 1 : 511;
      const int tn = dir ? (511 - stn) : stn;
      const u16* gp = G + (size_t)(tn * 32 + bg * 8 + bu) * 2048 + dir * 1024 + s64 + ju;
      gn0 = gp[0]; gn1 = gp[256]; gn2 = gp[512]; gn3 = gp[768];
    }
    // MFMA phase: out[row][b] = W[row][:] . h[:][b]  (3-term hi/lo split)
    floatx4 acc0 = {0,0,0,0}, acc1 = {0,0,0,0};
    #pragma unroll
    for (int ks = 0; ks < 8; ++ks) {
      short8v bhi = *(const short8v*)&hhi_lds[lr][ks * 32 + q * 8];
      short8v blo = *(const short8v*)&hlo_lds[lr][ks * 32 + q * 8];
      acc0 = __builtin_amdgcn_mfma_f32_16x16x32_bf16(Ahi[0][ks], bhi, acc0, 0, 0, 0);
      acc1 = __builtin_amdgcn_mfma_f32_16x16x32_bf16(Ahi[1][ks], bhi, acc1, 0, 0, 0);
      acc0 = __builtin_amdgcn_mfma_f32_16x16x32_bf16(Alo[0][ks], bhi, acc0, 0, 0, 0);
      acc1 = __builtin_amdgcn_mfma_f32_16x16x32_bf16(Alo[1][ks], bhi, acc1, 0, 0, 0);
      acc0 = __builtin_amdgcn_mfma_f32_16x16x32_bf16(Ahi[0][ks], blo, acc0, 0, 0, 0);
      acc1 = __builtin_amdgcn_mfma_f32_16x16x32_bf16(Ahi[1][ks], blo, acc1, 0, 0, 0);
    }
    // C layout: col(b)=lane&15, row(jj)=quad*4+reg
    #pragma unroll
    for (int reg = 0; reg < 4; ++reg) {
      part[(type * 64 + jjb +      q * 4 + reg) * 17 + lr] = acc0[reg];
      part[(type * 64 + jjb + 16 + q * 4 + reg) * 17 + lr] = acc1[reg];
    }
    __syncthreads();   // B2 (drains G prefetch too)
    // updater phase: all 512 threads, one (b,jj) each
    float si = bf2f(gv0) + part[(0 * 64 + ju) * 17 + bu];
    float sf = bf2f(gv1) + part[(1 * 64 + ju) * 17 + bu];
    float sg = bf2f(gv2) + part[(2 * 64 + ju) * 17 + bu];
    float so = bf2f(gv3) + part[(3 * 64 + ju) * 17 + bu];
    float cold = clds[tid];
    float ig = sigf(si), fg = sigf(sf), gg = tanh_f(sg), og = sigf(so);
    float cn = fg * cold + ig * gg;
    float hn = og * tanh_f(cn);
    clds[tid] = cn;
    u16 hhi = f2bf(hn);
    u16 hlo = f2bf(hn - bf2f(hhi));
    u32 hv = ((u32)hhi << 16) | hlo;
    __hip_atomic_store(hb + (par ^ 1) * 2048 + bu * 256 + s64 + ju, hv,
                       __ATOMIC_RELAXED, __HIP_MEMORY_SCOPE_AGENT);
    // X output issued before the drain so nothing is outstanding at next poll
    const size_t oidx = ((size_t)t * 32 + (bg * 8 + bu)) * 512 + dir * 256 + s64 + ju;
    if (Xbf) Xbf[oidx] = hhi;
    else     Xf[oidx] = hn;
    // per-wave drain of h+X stores, then per-wave single-writer flag line
    asm volatile("s_waitcnt vmcnt(0)" ::: "memory");
    if (lane == 0)
      __hip_atomic_store((u32*)&flags[(bu * 4 + slice) * 32], (u32)(st + 1),
                         __ATOMIC_RELAXED, __HIP_MEMORY_SCOPE_AGENT);
  }
}

// ---------------- LayerNorm + classifier head; logits -> d_out+1 ----------------
__global__ void head_k(const float* __restrict__ X2, const float* __restrict__ gamma,
                       const float* __restrict__ beta, const float* __restrict__ cw,
                       const float* __restrict__ cb, float* __restrict__ out) {
  __shared__ float red[9][64];
  const int m = blockIdx.x, lane = threadIdx.x;
  const int s = m >> 5, b = m & 31;
  const float4* xp = (const float4*)(X2 + (size_t)m * 512) + lane * 2;
  float4 x0 = xp[0], x1 = xp[1];
  float sm = x0.x + x0.y + x0.z + x0.w + x1.x + x1.y + x1.z + x1.w;
  float sq = x0.x*x0.x + x0.y*x0.y + x0.z*x0.z + x0.w*x0.w
           + x1.x*x1.x + x1.y*x1.y + x1.z*x1.z + x1.w*x1.w;
  #pragma unroll
  for (int off = 32; off > 0; off >>= 1) {
    sm += __shfl_xor(sm, off, 64);
    sq += __shfl_xor(sq, off, 64);
  }
  const float mu = sm * (1.0f / 512.0f);
  const float var = sq * (1.0f / 512.0f) - mu * mu;
  const float rs = rsqrtf(var + 1e-5f);
  const float4* gp = (const float4*)gamma + lane * 2;
  const float4* bp = (const float4*)beta + lane * 2;
  float4 g0 = gp[0], g1 = gp[1], be0 = bp[0], be1 = bp[1];
  float nv[8];
  nv[0] = (x0.x - mu) * rs * g0.x + be0.x;
  nv[1] = (x0.y - mu) * rs * g0.y + be0.y;
  nv[2] = (x0.z - mu) * rs * g0.z + be0.z;
  nv[3] = (x0.w - mu) * rs * g0.w + be0.w;
  nv[4] = (x1.x - mu) * rs * g1.x + be1.x;
  nv[5] = (x1.y - mu) * rs * g1.y + be1.y;
  nv[6] = (x1.z - mu) * rs * g1.z + be1.z;
  nv[7] = (x1.w - mu) * rs * g1.w + be1.w;
  #pragma unroll
  for (int c = 0; c < 9; ++c) {
    const float4* wp = (const float4*)(cw + (size_t)c * 512) + lane * 2;
    float4 w0 = wp[0], w1 = wp[1];
    red[c][lane] = nv[0]*w0.x + nv[1]*w0.y + nv[2]*w0.z + nv[3]*w0.w
                 + nv[4]*w1.x + nv[5]*w1.y + nv[6]*w1.z + nv[7]*w1.w;
  }
  __syncthreads();
  if (lane < 9) {
    float t = 0.f;
    for (int i = 0; i < 64; ++i) t += red[lane][i];
    out[1 + ((size_t)b * 512 + s) * 9 + lane] = t + cb[lane];
  }
}

// ---------------- CRF NLL: one wave per batch element ----------------
__global__ void crf_k(const float* __restrict__ logits, const int* __restrict__ labels,
                      const int* __restrict__ lens, const float* __restrict__ tr,
                      float* __restrict__ loss) {
  const int b = blockIdx.x, lane = threadIdx.x;
  const int len = lens[b];
  float trj[9];
  #pragma unroll
  for (int i = 0; i < 9; ++i) trj[i] = 0.f;
  if (lane < 9) {
    #pragma unroll
    for (int i = 0; i < 9; ++i) trj[i] = tr[i * 11 + lane];
  }
  float alpha = -1e30f;
  if (lane < 9) alpha = tr[9 * 11 + lane] + logits[(size_t)b * 512 * 9 + lane];
  for (int t = 1; t < len; ++t) {
    float e = (lane < 9) ? logits[((size_t)b * 512 + t) * 9 + lane] : 0.f;
    float v[9];
    float mx = -1e30f;
    #pragma unroll
    for (int i = 0; i < 9; ++i) {
      v[i] = __shfl(alpha, i, 64) + trj[i];
      mx = fmaxf(mx, v[i]);
    }
    float ss = 0.f;
    #pragma unroll
    for (int i = 0; i < 9; ++i) ss += __expf(v[i] - mx);
    float na = mx + __logf(ss) + e;
    if (lane < 9) alpha = na;
  }
  float fin = (lane < 9) ? alpha + tr[lane * 11 + 10] : -1e30f;
  float mx = fin;
  #pragma unroll
  for (int off = 8; off > 0; off >>= 1) mx = fmaxf(mx, __shfl_xor(mx, off, 64));
  float es = (lane < 9) ? __expf(fin - mx) : 0.f;
  #pragma unroll
  for (int off = 8; off > 0; off >>= 1) es += __shfl_xor(es, off, 64);
  const float logZ = mx + __logf(es);
  float emit = 0.f, ts = 0.f;
  for (int t = lane; t < len; t += 64) {
    int y = labels[b * 512 + t];
    emit += logits[((size_t)b * 512 + t) * 9 + y];
  }
  for (int t = 1 + lane; t < len; t += 64) {
    int y0 = labels[b * 512 + t - 1], y1 = labels[b * 512 + t];
    ts += tr[y0 * 11 + y1];
  }
  #pragma unroll
  for (int off = 32; off > 0; off >>= 1) {
    emit += __shfl_xor(emit, off, 64);
    ts += __shfl_xor(ts, off, 64);
  }
  if (lane == 0) {
    int y0 = labels[b * 512], yl = labels[b * 512 + len - 1];
    float gold = emit + ts + tr[9 * 11 + y0] + tr[yl * 11 + 10];
    atomicAdd(loss, (logZ - gold) * (1.0f / 32.0f));
  }
}

extern "C" void kernel_launch(void* const* d_in, const int* in_sizes, int n_in,
                              void* d_out, int out_size, void* d_ws, size_t ws_size,
                              hipStream_t stream) {
  const int* ids = (const int*)d_in[0];
  const int* amask = (const int*)d_in[1];
  const int* lens = (const int*)d_in[2];
  const int* labels = (const int*)d_in[3];
  const float* emb = (const float*)d_in[4];
  const float* w_ih = (const float*)d_in[5];
  const float* w_hh = (const float*)d_in[6];
  const float* b_ih = (const float*)d_in[7];
  const float* b_hh = (const float*)d_in[8];
  const float* gamma = (const float*)d_in[9];
  const float* beta = (const float*)d_in[10];
  const float* cw = (const float*)d_in[11];
  const float* cb = (const float*)d_in[12];
  const float* tr = (const float*)d_in[13];
  (void)in_sizes; (void)n_in; (void)out_size;

  if (ws_size < WS_NEEDED) return;  // workspace too small -> clean failure

  char* p = (char*)d_ws;
  u16* X0 = (u16*)p;      p += (size_t)16384 * 512 * 2;        // 16.78 MB
  u16* Wbf = (u16*)p;     p += (size_t)2 * 2 * 1024 * 512 * 2; // 4.19 MB
  u16* G = (u16*)p;       p += (size_t)16384 * 2048 * 2;       // 67.1 MB
  u16* X1 = (u16*)p;      p += (size_t)16384 * 512 * 2;        // 16.78 MB
  float* X2 = (float*)p;  p += (size_t)16384 * 512 * 4;        // 33.55 MB
  u32* Hb = (u32*)p;      p += (size_t)32768 * 4;              // 128 KB
  int* flg = (int*)p;     p += 32768;                          // 8x8x4 lines x 128B
  float* out = (float*)d_out;

  prep_k<<<16384, 64, 0, stream>>>(ids, amask, emb, X0);
  conv_k<<<1024, 256, 0, stream>>>(w_ih, Wbf, 262144);
  zero_k<<<16, 512, 0, stream>>>(flg, out);
  // Layer 0
  gemm_k<<<dim3(256, 32), 256, 0, stream>>>(X0, Wbf, b_ih, b_hh, G);
  rec_k<<<32, 512, 0, stream>>>(G, w_hh, Hb, flg, X1, nullptr);
  zero_k<<<16, 512, 0, stream>>>(flg, out);
  // Layer 1
  gemm_k<<<dim3(256, 32), 256, 0, stream>>>(X1, Wbf + 2 * 1024 * 512,
                                            b_ih + 2048, b_hh + 2048, G);
  rec_k<<<32, 512, 0, stream>>>(G, w_hh + 2 * 1024 * 256, Hb, flg,
                                nullptr, X2);
  // Head + CRF
  head_k<<<16384, 64, 0, stream>>>(X2, gamma, beta, cw, cb, out);
  crf_k<<<32, 64, 0, stream>>>(out + 1, labels, lens, tr, out);
}

// Round 7
// 2898.587 us; speedup vs baseline: 1.4192x; 1.1802x over previous
//
#include <hip/hip_runtime.h>

// Problem dims
#define B_ 32
#define S_ 512
#define D_ 512
#define H_ 256

typedef float floatx4 __attribute__((ext_vector_type(4)));
typedef short short8v __attribute__((ext_vector_type(8)));
typedef unsigned short u16;
typedef unsigned int u32;
typedef unsigned long long u64;

#define WS_NEEDED 138575872ull

__device__ __forceinline__ u16 f2bf(float f) {
  u32 x = __float_as_uint(f);
  x += 0x7fffu + ((x >> 16) & 1u);   // RNE
  return (u16)(x >> 16);
}
__device__ __forceinline__ float bf2f(u16 h) {
  return __uint_as_float(((u32)h) << 16);
}
__device__ __forceinline__ float decode_hl(u32 v) {
  return bf2f((u16)(v >> 16)) + bf2f((u16)(v & 0xffffu));
}
__device__ __forceinline__ float sigf(float x) {
  return 1.0f / (1.0f + __expf(-x));
}
__device__ __forceinline__ float tanh_f(float x) {
  float e = __expf(-2.0f * fabsf(x));
  float r = (1.0f - e) / (1.0f + e);
  return copysignf(r, x);
}

struct alignas(16) U16x8 { u16 v[8]; };

// ---------------- embedding -> X0 bf16, time-major (m = s*32+b, 512 feats) ----------------
__global__ void prep_k(const int* __restrict__ ids, const int* __restrict__ amask,
                       const float* __restrict__ emb, u16* __restrict__ X0) {
  int m = blockIdx.x;            // m = s*32 + b
  int lane = threadIdx.x;        // 64
  int s = m >> 5, b = m & 31;
  int id = ids[b * S_ + s];
  int mk = amask[b * S_ + s];
  const float4* src = (const float4*)(emb + (size_t)id * D_) + lane * 2;
  float4 v0 = src[0], v1 = src[1];
  if (!mk) { v0 = make_float4(0,0,0,0); v1 = make_float4(0,0,0,0); }
  U16x8 o;
  o.v[0]=f2bf(v0.x); o.v[1]=f2bf(v0.y); o.v[2]=f2bf(v0.z); o.v[3]=f2bf(v0.w);
  o.v[4]=f2bf(v1.x); o.v[5]=f2bf(v1.y); o.v[6]=f2bf(v1.z); o.v[7]=f2bf(v1.w);
  *(U16x8*)(X0 + (size_t)m * D_ + lane * 8) = o;
}

// ---------------- fp32 -> bf16 weight convert (w_ih, 2*2*1024*512 elems) ----------------
__global__ void conv_k(const float* __restrict__ w, u16* __restrict__ wbf, int n8) {
  int idx = blockIdx.x * blockDim.x + threadIdx.x;
  if (idx >= n8) return;
  const float4* s = (const float4*)w + (size_t)idx * 2;
  float4 v0 = s[0], v1 = s[1];
  U16x8 o;
  o.v[0]=f2bf(v0.x); o.v[1]=f2bf(v0.y); o.v[2]=f2bf(v0.z); o.v[3]=f2bf(v0.w);
  o.v[4]=f2bf(v1.x); o.v[5]=f2bf(v1.y); o.v[6]=f2bf(v1.z); o.v[7]=f2bf(v1.w);
  *(U16x8*)(wbf + (size_t)idx * 8) = o;
}

// ---------------- zero sync flags / loss ----------------
// flags: 8 groups x 32 ints (one 128B line per group; first 4 ints used)
__global__ void zero_k(int* __restrict__ flg, float* __restrict__ loss) {
  int idx = threadIdx.x;
  if (idx < 256) flg[idx] = 0;
  if (idx == 0) *loss = 0.f;
}

// ---------------- bf16 MFMA GEMM: G[m][n] = A[m][:] . W[n][:] + bih[n] + bhh[n] ----------------
__global__ void gemm_k(const u16* __restrict__ A, const u16* __restrict__ W,
                       const float* __restrict__ bih, const float* __restrict__ bhh,
                       u16* __restrict__ G) {
  __shared__ short Asm[64 * 40];
  __shared__ short Bsm[64 * 40];
  const int tid = threadIdx.x;
  const int m0 = blockIdx.x * 64, n0 = blockIdx.y * 64;
  const int wid = tid >> 6, lane = tid & 63;
  const int quad = lane >> 4, lr = lane & 15;
  const int wm = (wid >> 1) * 32, wn = (wid & 1) * 32;
  const int lrow = tid >> 2, lk = (tid & 3) * 8;
  floatx4 acc00 = {0,0,0,0}, acc01 = {0,0,0,0}, acc10 = {0,0,0,0}, acc11 = {0,0,0,0};
  for (int kt = 0; kt < 16; ++kt) {
    const int k0 = kt * 32;
    uint4 av = *(const uint4*)(A + (size_t)(m0 + lrow) * 512 + k0 + lk);
    uint4 bv = *(const uint4*)(W + (size_t)(n0 + lrow) * 512 + k0 + lk);
    __syncthreads();
    *(uint4*)&Asm[lrow * 40 + lk] = av;
    *(uint4*)&Bsm[lrow * 40 + lk] = bv;
    __syncthreads();
    short8v a0 = *(const short8v*)&Asm[(wm + lr) * 40 + quad * 8];
    short8v a1 = *(const short8v*)&Asm[(wm + 16 + lr) * 40 + quad * 8];
    short8v b0 = *(const short8v*)&Bsm[(wn + lr) * 40 + quad * 8];
    short8v b1 = *(const short8v*)&Bsm[(wn + 16 + lr) * 40 + quad * 8];
    acc00 = __builtin_amdgcn_mfma_f32_16x16x32_bf16(a0, b0, acc00, 0, 0, 0);
    acc01 = __builtin_amdgcn_mfma_f32_16x16x32_bf16(a0, b1, acc01, 0, 0, 0);
    acc10 = __builtin_amdgcn_mfma_f32_16x16x32_bf16(a1, b0, acc10, 0, 0, 0);
    acc11 = __builtin_amdgcn_mfma_f32_16x16x32_bf16(a1, b1, acc11, 0, 0, 0);
  }
  #pragma unroll
  for (int j = 0; j < 2; ++j) {
    const int n = n0 + wn + j * 16 + lr;
    const float bias = bih[n] + bhh[n];
    #pragma unroll
    for (int i = 0; i < 2; ++i) {
      const int mb = m0 + wm + i * 16 + quad * 4;
      floatx4 av = (i == 0) ? (j == 0 ? acc00 : acc01) : (j == 0 ? acc10 : acc11);
      #pragma unroll
      for (int rr = 0; rr < 4; ++rr) {
        G[(size_t)(mb + rr) * 2048 + n] = f2bf(av[rr] + bias);
      }
    }
  }
}

// ---------------- LSTM recurrence via MFMA, weights resident in VGPRs ----------------
// grid 32 = dir(2) x slice(4) x bg(4); 512 threads (8 waves).
// R4-proven sync skeleton: h store (relaxed agent) -> B3 __syncthreads (drains
// all waves' vmcnt) -> ONE tid0 flag store per wg into the group's shared
// 128B flag line; consumer polls the line with two u64 loads.
// + R6's G pipeline: next step's gates prefetched after B1, drained by B2.
// + X outputs staged in LDS and dumped every 8 steps as coalesced dwordx4
//   AFTER the flag store (write-ack cost amortized 8x off the critical path).
__launch_bounds__(512, 1)
__global__ void rec_k(const u16* __restrict__ G, const float* __restrict__ whh_l,
                      u32* __restrict__ Hbuf, int* __restrict__ flg,
                      u16* __restrict__ Xbf, u32* __restrict__ Xu) {
  __shared__ u16 hhi_lds[16][264];   // [batch(8 real+8 zero)][k=256 pad 264]
  __shared__ u16 hlo_lds[16][264];
  __shared__ float part[4 * 64 * 17]; // [type][jj][b pad17]
  __shared__ float clds[512];         // c state: [b][jj] = clds[tid]
  __shared__ u32 xst[8 * 512];        // X staging, 8 steps (u16 view for layer0)

  const int tid = threadIdx.x;
  const int dir = blockIdx.x >> 4;
  const int slice = (blockIdx.x >> 2) & 3;
  const int bg = blockIdx.x & 3;
  const int s64 = slice * 64;
  const int w = tid >> 6;
  const int lane = tid & 63;
  const int q = lane >> 4;      // quad
  const int lr = lane & 15;
  const int type = w >> 1;      // gate type for MFMA phase
  const int jjb = (w & 1) * 32; // hidden base within 64-slice

  const float* whh = whh_l + (size_t)dir * (1024 * 256);

  // ---- one-time: preload Whh slice into VGPR A-fragments (hi + lo residual) ----
  short8v Ahi[2][8], Alo[2][8];
  #pragma unroll
  for (int ti = 0; ti < 2; ++ti) {
    const float* wrow = whh + (size_t)(type * 256 + s64 + jjb + ti * 16 + lr) * 256;
    #pragma unroll
    for (int ks = 0; ks < 8; ++ks) {
      const float* pk = wrow + ks * 32 + q * 8;
      short8v hi, lo;
      #pragma unroll
      for (int j = 0; j < 8; ++j) {
        float v = pk[j];
        u16 hb = f2bf(v);
        hi[j] = (short)hb;
        lo[j] = (short)f2bf(v - bf2f(hb));
      }
      Ahi[ti][ks] = hi; Alo[ti][ks] = lo;
    }
  }
  for (int i = tid; i < 16 * 264; i += 512) {
    ((u16*)hhi_lds)[i] = 0; ((u16*)hlo_lds)[i] = 0;
  }
  clds[tid] = 0.f;

  int* flags = flg + (dir * 4 + bg) * 32;           // one 128B line per group
  u32* hb = Hbuf + (size_t)(dir * 4 + bg) * 4096;   // 2 parity * 2048 u32
  const int bu = w;       // updater: batch in group (0..7)
  const int ju = lane;    // updater: hidden in slice (0..63)

  // preamble: load G[st=0]
  u16 gn0, gn1, gn2, gn3;
  {
    const int t0 = dir ? 511 : 0;
    const u16* gp = G + (size_t)(t0 * 32 + bg * 8 + bu) * 2048 + dir * 1024 + s64 + ju;
    gn0 = gp[0]; gn1 = gp[256]; gn2 = gp[512]; gn3 = gp[768];
  }
  __syncthreads();

  for (int st = 0; st < 512; ++st) {
    const int t = dir ? (511 - st) : st;
    const int par = st & 1;
    // current step's gates (prefetched last iteration, already drained)
    const u16 gv0 = gn0, gv1 = gn1, gv2 = gn2, gv3 = gn3;
    if (st > 0) {
      // all threads poll the group's single flag line (4 slice flags)
      const u32 target = (u32)st;
      const u64* f64 = (const u64*)flags;
      int spin = 0;
      for (;;) {
        u64 a = __hip_atomic_load(f64,     __ATOMIC_RELAXED, __HIP_MEMORY_SCOPE_AGENT);
        u64 b = __hip_atomic_load(f64 + 1, __ATOMIC_RELAXED, __HIP_MEMORY_SCOPE_AGENT);
        u32 f0 = (u32)a, f1 = (u32)(a >> 32), f2 = (u32)b, f3 = (u32)(b >> 32);
        if (f0 >= target && f1 >= target && f2 >= target && f3 >= target) break;
        if (++spin > (1 << 20)) break;   // hang-avoidance only
      }
      asm volatile("" ::: "memory");     // no hoisting h loads above the poll
    }
    // h_prev: packed u32 loads -> unpack -> LDS (B-operand layout [b][k])
    if (st > 0) {
      const u64* src = (const u64*)(hb + par * 2048);
      u64 p0 = __hip_atomic_load(src + 2 * tid,     __ATOMIC_RELAXED, __HIP_MEMORY_SCOPE_AGENT);
      u64 p1 = __hip_atomic_load(src + 2 * tid + 1, __ATOMIC_RELAXED, __HIP_MEMORY_SCOPE_AGENT);
      u32 c0 = (u32)p0, c1 = (u32)(p0 >> 32), c2 = (u32)p1, c3 = (u32)(p1 >> 32);
      const int b = tid >> 6, k4 = (tid & 63) * 4;
      u64 hiq = (u64)(c0 >> 16) | ((u64)(c1 >> 16) << 16)
              | ((u64)(c2 >> 16) << 32) | ((u64)(c3 >> 16) << 48);
      u64 loq = (u64)(c0 & 0xffffu) | ((u64)(c1 & 0xffffu) << 16)
              | ((u64)(c2 & 0xffffu) << 32) | ((u64)(c3 & 0xffffu) << 48);
      *(u64*)&hhi_lds[b][k4] = hiq;
      *(u64*)&hlo_lds[b][k4] = loq;
    }
    __syncthreads();   // B1 (drains h loads; also preamble G on st=0)
    // prefetch NEXT step's G: hidden under MFMA, drained by B2's vmcnt(0)
    {
      const int stn = (st < 511) ? st + 1 : 511;
      const int tn = dir ? (511 - stn) : stn;
      const u16* gp = G + (size_t)(tn * 32 + bg * 8 + bu) * 2048 + dir * 1024 + s64 + ju;
      gn0 = gp[0]; gn1 = gp[256]; gn2 = gp[512]; gn3 = gp[768];
    }
    // MFMA phase: out[row][b] = W[row][:] . h[:][b]  (3-term hi/lo split)
    floatx4 acc0 = {0,0,0,0}, acc1 = {0,0,0,0};
    #pragma unroll
    for (int ks = 0; ks < 8; ++ks) {
      short8v bhi = *(const short8v*)&hhi_lds[lr][ks * 32 + q * 8];
      short8v blo = *(const short8v*)&hlo_lds[lr][ks * 32 + q * 8];
      acc0 = __builtin_amdgcn_mfma_f32_16x16x32_bf16(Ahi[0][ks], bhi, acc0, 0, 0, 0);
      acc1 = __builtin_amdgcn_mfma_f32_16x16x32_bf16(Ahi[1][ks], bhi, acc1, 0, 0, 0);
      acc0 = __builtin_amdgcn_mfma_f32_16x16x32_bf16(Alo[0][ks], bhi, acc0, 0, 0, 0);
      acc1 = __builtin_amdgcn_mfma_f32_16x16x32_bf16(Alo[1][ks], bhi, acc1, 0, 0, 0);
      acc0 = __builtin_amdgcn_mfma_f32_16x16x32_bf16(Ahi[0][ks], blo, acc0, 0, 0, 0);
      acc1 = __builtin_amdgcn_mfma_f32_16x16x32_bf16(Ahi[1][ks], blo, acc1, 0, 0, 0);
    }
    // C layout: col(b)=lane&15, row(jj)=quad*4+reg
    #pragma unroll
    for (int reg = 0; reg < 4; ++reg) {
      part[(type * 64 + jjb +      q * 4 + reg) * 17 + lr] = acc0[reg];
      part[(type * 64 + jjb + 16 + q * 4 + reg) * 17 + lr] = acc1[reg];
    }
    __syncthreads();   // B2 (drains G prefetch too)
    // updater phase: all 512 threads, one (b,jj) each
    float si = bf2f(gv0) + part[(0 * 64 + ju) * 17 + bu];
    float sf = bf2f(gv1) + part[(1 * 64 + ju) * 17 + bu];
    float sg = bf2f(gv2) + part[(2 * 64 + ju) * 17 + bu];
    float so = bf2f(gv3) + part[(3 * 64 + ju) * 17 + bu];
    float cold = clds[tid];
    float ig = sigf(si), fg = sigf(sf), gg = tanh_f(sg), og = sigf(so);
    float cn = fg * cold + ig * gg;
    float hn = og * tanh_f(cn);
    clds[tid] = cn;
    u16 hhi = f2bf(hn);
    u16 hlo = f2bf(hn - bf2f(hhi));
    u32 hv = ((u32)hhi << 16) | hlo;
    __hip_atomic_store(hb + (par ^ 1) * 2048 + bu * 256 + s64 + ju, hv,
                       __ATOMIC_RELAXED, __HIP_MEMORY_SCOPE_AGENT);
    // stage X in LDS (dumped every 8 steps, off the signal path)
    if (Xbf) ((u16*)xst)[(st & 7) * 512 + tid] = hhi;
    else     xst[(st & 7) * 512 + tid] = hv;
    __syncthreads();   // B3: drains ALL waves' h stores; makes xst visible
    if (tid == 0)
      __hip_atomic_store((u32*)&flags[slice], (u32)(st + 1),
                         __ATOMIC_RELAXED, __HIP_MEMORY_SCOPE_AGENT);
    // batched X dump: coalesced dwordx4, issued after the flag store
    if ((st & 7) == 7) {
      const int st0 = st - 7;
      if (Xbf) {
        const int slot = tid >> 6, r = tid & 63;
        const int b = r >> 3, f8 = (r & 7) * 8;
        const int tt = dir ? (511 - (st0 + slot)) : (st0 + slot);
        uint4 vv = *(const uint4*)&((u16*)xst)[slot * 512 + b * 64 + f8];
        *(uint4*)(Xbf + ((size_t)tt * 32 + bg * 8 + b) * 512 + dir * 256 + s64 + f8) = vv;
      } else {
        #pragma unroll
        for (int half = 0; half < 2; ++half) {
          const int seg = half * 512 + tid;
          const int slot = seg >> 7, rem = seg & 127;
          const int b = rem >> 4, f4 = (rem & 15) * 4;
          const int tt = dir ? (511 - (st0 + slot)) : (st0 + slot);
          uint4 vv = *(const uint4*)&xst[slot * 512 + b * 64 + f4];
          *(uint4*)(Xu + ((size_t)tt * 32 + bg * 8 + b) * 512 + dir * 256 + s64 + f4) = vv;
        }
      }
    }
  }
}

// ---------------- LayerNorm + classifier head; logits -> d_out+1 ----------------
// X2u: packed (bf16hi<<16|bf16lo) per element; decode = bf2f(hi)+bf2f(lo)
__global__ void head_k(const u32* __restrict__ X2u, const float* __restrict__ gamma,
                       const float* __restrict__ beta, const float* __restrict__ cw,
                       const float* __restrict__ cb, float* __restrict__ out) {
  __shared__ float red[9][64];
  const int m = blockIdx.x, lane = threadIdx.x;
  const int s = m >> 5, b = m & 31;
  const uint4* xp = (const uint4*)(X2u + (size_t)m * 512) + lane * 2;
  uint4 a0 = xp[0], a1 = xp[1];
  float x[8];
  x[0] = decode_hl(a0.x); x[1] = decode_hl(a0.y);
  x[2] = decode_hl(a0.z); x[3] = decode_hl(a0.w);
  x[4] = decode_hl(a1.x); x[5] = decode_hl(a1.y);
  x[6] = decode_hl(a1.z); x[7] = decode_hl(a1.w);
  float sm = 0.f, sq = 0.f;
  #pragma unroll
  for (int i = 0; i < 8; ++i) { sm += x[i]; sq += x[i] * x[i]; }
  #pragma unroll
  for (int off = 32; off > 0; off >>= 1) {
    sm += __shfl_xor(sm, off, 64);
    sq += __shfl_xor(sq, off, 64);
  }
  const float mu = sm * (1.0f / 512.0f);
  const float var = sq * (1.0f / 512.0f) - mu * mu;
  const float rs = rsqrtf(var + 1e-5f);
  const float4* gp = (const float4*)gamma + lane * 2;
  const float4* bp = (const float4*)beta + lane * 2;
  float4 g0 = gp[0], g1 = gp[1], be0 = bp[0], be1 = bp[1];
  float nv[8];
  nv[0] = (x[0] - mu) * rs * g0.x + be0.x;
  nv[1] = (x[1] - mu) * rs * g0.y + be0.y;
  nv[2] = (x[2] - mu) * rs * g0.z + be0.z;
  nv[3] = (x[3] - mu) * rs * g0.w + be0.w;
  nv[4] = (x[4] - mu) * rs * g1.x + be1.x;
  nv[5] = (x[5] - mu) * rs * g1.y + be1.y;
  nv[6] = (x[6] - mu) * rs * g1.z + be1.z;
  nv[7] = (x[7] - mu) * rs * g1.w + be1.w;
  #pragma unroll
  for (int c = 0; c < 9; ++c) {
    const float4* wp = (const float4*)(cw + (size_t)c * 512) + lane * 2;
    float4 w0 = wp[0], w1 = wp[1];
    red[c][lane] = nv[0]*w0.x + nv[1]*w0.y + nv[2]*w0.z + nv[3]*w0.w
                 + nv[4]*w1.x + nv[5]*w1.y + nv[6]*w1.z + nv[7]*w1.w;
  }
  __syncthreads();
  if (lane < 9) {
    float t = 0.f;
    for (int i = 0; i < 64; ++i) t += red[lane][i];
    out[1 + ((size_t)b * 512 + s) * 9 + lane] = t + cb[lane];
  }
}

// ---------------- CRF NLL: one wave per batch element ----------------
__global__ void crf_k(const float* __restrict__ logits, const int* __restrict__ labels,
                      const int* __restrict__ lens, const float* __restrict__ tr,
                      float* __restrict__ loss) {
  const int b = blockIdx.x, lane = threadIdx.x;
  const int len = lens[b];
  float trj[9];
  #pragma unroll
  for (int i = 0; i < 9; ++i) trj[i] = 0.f;
  if (lane < 9) {
    #pragma unroll
    for (int i = 0; i < 9; ++i) trj[i] = tr[i * 11 + lane];
  }
  float alpha = -1e30f;
  if (lane < 9) alpha = tr[9 * 11 + lane] + logits[(size_t)b * 512 * 9 + lane];
  for (int t = 1; t < len; ++t) {
    float e = (lane < 9) ? logits[((size_t)b * 512 + t) * 9 + lane] : 0.f;
    float v[9];
    float mx = -1e30f;
    #pragma unroll
    for (int i = 0; i < 9; ++i) {
      v[i] = __shfl(alpha, i, 64) + trj[i];
      mx = fmaxf(mx, v[i]);
    }
    float ss = 0.f;
    #pragma unroll
    for (int i = 0; i < 9; ++i) ss += __expf(v[i] - mx);
    float na = mx + __logf(ss) + e;
    if (lane < 9) alpha = na;
  }
  float fin = (lane < 9) ? alpha + tr[lane * 11 + 10] : -1e30f;
  float mx = fin;
  #pragma unroll
  for (int off = 8; off > 0; off >>= 1) mx = fmaxf(mx, __shfl_xor(mx, off, 64));
  float es = (lane < 9) ? __expf(fin - mx) : 0.f;
  #pragma unroll
  for (int off = 8; off > 0; off >>= 1) es += __shfl_xor(es, off, 64);
  const float logZ = mx + __logf(es);
  float emit = 0.f, ts = 0.f;
  for (int t = lane; t < len; t += 64) {
    int y = labels[b * 512 + t];
    emit += logits[((size_t)b * 512 + t) * 9 + y];
  }
  for (int t = 1 + lane; t < len; t += 64) {
    int y0 = labels[b * 512 + t - 1], y1 = labels[b * 512 + t];
    ts += tr[y0 * 11 + y1];
  }
  #pragma unroll
  for (int off = 32; off > 0; off >>= 1) {
    emit += __shfl_xor(emit, off, 64);
    ts += __shfl_xor(ts, off, 64);
  }
  if (lane == 0) {
    int y0 = labels[b * 512], yl = labels[b * 512 + len - 1];
    float gold = emit + ts + tr[9 * 11 + y0] + tr[yl * 11 + 10];
    atomicAdd(loss, (logZ - gold) * (1.0f / 32.0f));
  }
}

extern "C" void kernel_launch(void* const* d_in, const int* in_sizes, int n_in,
                              void* d_out, int out_size, void* d_ws, size_t ws_size,
                              hipStream_t stream) {
  const int* ids = (const int*)d_in[0];
  const int* amask = (const int*)d_in[1];
  const int* lens = (const int*)d_in[2];
  const int* labels = (const int*)d_in[3];
  const float* emb = (const float*)d_in[4];
  const float* w_ih = (const float*)d_in[5];
  const float* w_hh = (const float*)d_in[6];
  const float* b_ih = (const float*)d_in[7];
  const float* b_hh = (const float*)d_in[8];
  const float* gamma = (const float*)d_in[9];
  const float* beta = (const float*)d_in[10];
  const float* cw = (const float*)d_in[11];
  const float* cb = (const float*)d_in[12];
  const float* tr = (const float*)d_in[13];
  (void)in_sizes; (void)n_in; (void)out_size;

  if (ws_size < WS_NEEDED) return;  // workspace too small -> clean failure

  char* p = (char*)d_ws;
  u16* X0 = (u16*)p;      p += (size_t)16384 * 512 * 2;        // 16.78 MB
  u16* Wbf = (u16*)p;     p += (size_t)2 * 2 * 1024 * 512 * 2; // 4.19 MB
  u16* G = (u16*)p;       p += (size_t)16384 * 2048 * 2;       // 67.1 MB
  u16* X1 = (u16*)p;      p += (size_t)16384 * 512 * 2;        // 16.78 MB
  u32* X2u = (u32*)p;     p += (size_t)16384 * 512 * 4;        // 33.55 MB
  u32* Hb = (u32*)p;      p += (size_t)32768 * 4;              // 128 KB
  int* flg = (int*)p;     p += 32768;
  float* out = (float*)d_out;

  prep_k<<<16384, 64, 0, stream>>>(ids, amask, emb, X0);
  conv_k<<<1024, 256, 0, stream>>>(w_ih, Wbf, 262144);
  zero_k<<<1, 256, 0, stream>>>(flg, out);
  // Layer 0
  gemm_k<<<dim3(256, 32), 256, 0, stream>>>(X0, Wbf, b_ih, b_hh, G);
  rec_k<<<32, 512, 0, stream>>>(G, w_hh, Hb, flg, X1, nullptr);
  zero_k<<<1, 256, 0, stream>>>(flg, out);
  // Layer 1
  gemm_k<<<dim3(256, 32), 256, 0, stream>>>(X1, Wbf + 2 * 1024 * 512,
                                            b_ih + 2048, b_hh + 2048, G);
  rec_k<<<32, 512, 0, stream>>>(G, w_hh + 2 * 1024 * 256, Hb, flg,
                                nullptr, X2u);
  // Head + CRF
  head_k<<<16384, 64, 0, stream>>>(X2u, gamma, beta, cw, cb, out);
  crf_k<<<32, 64, 0, stream>>>(out + 1, labels, lens, tr, out);
}

// Round 8
// 2750.699 us; speedup vs baseline: 1.4955x; 1.0538x over previous
//
#include <hip/hip_runtime.h>

// Problem dims
#define B_ 32
#define S_ 512
#define D_ 512
#define H_ 256

typedef float floatx4 __attribute__((ext_vector_type(4)));
typedef short short8v __attribute__((ext_vector_type(8)));
typedef unsigned short u16;
typedef unsigned int u32;
typedef unsigned long long u64;

#define WS_NEEDED 138575872ull

__device__ __forceinline__ u16 f2bf(float f) {
  u32 x = __float_as_uint(f);
  x += 0x7fffu + ((x >> 16) & 1u);   // RNE
  return (u16)(x >> 16);
}
__device__ __forceinline__ float bf2f(u16 h) {
  return __uint_as_float(((u32)h) << 16);
}
__device__ __forceinline__ float decode_hl(u32 v) {
  return bf2f((u16)(v >> 16)) + bf2f((u16)(v & 0xffffu));
}
__device__ __forceinline__ float sigf(float x) {
  return 1.0f / (1.0f + __expf(-x));
}
__device__ __forceinline__ float tanh_f(float x) {
  float e = __expf(-2.0f * fabsf(x));
  float r = (1.0f - e) / (1.0f + e);
  return copysignf(r, x);
}

struct alignas(16) U16x8 { u16 v[8]; };

// ---------------- embedding -> X0 bf16, time-major (m = s*32+b, 512 feats) ----------------
__global__ void prep_k(const int* __restrict__ ids, const int* __restrict__ amask,
                       const float* __restrict__ emb, u16* __restrict__ X0) {
  int m = blockIdx.x;            // m = s*32 + b
  int lane = threadIdx.x;        // 64
  int s = m >> 5, b = m & 31;
  int id = ids[b * S_ + s];
  int mk = amask[b * S_ + s];
  const float4* src = (const float4*)(emb + (size_t)id * D_) + lane * 2;
  float4 v0 = src[0], v1 = src[1];
  if (!mk) { v0 = make_float4(0,0,0,0); v1 = make_float4(0,0,0,0); }
  U16x8 o;
  o.v[0]=f2bf(v0.x); o.v[1]=f2bf(v0.y); o.v[2]=f2bf(v0.z); o.v[3]=f2bf(v0.w);
  o.v[4]=f2bf(v1.x); o.v[5]=f2bf(v1.y); o.v[6]=f2bf(v1.z); o.v[7]=f2bf(v1.w);
  *(U16x8*)(X0 + (size_t)m * D_ + lane * 8) = o;
}

// ---------------- fp32 -> bf16 weight convert (w_ih, 2*2*1024*512 elems) ----------------
__global__ void conv_k(const float* __restrict__ w, u16* __restrict__ wbf, int n8) {
  int idx = blockIdx.x * blockDim.x + threadIdx.x;
  if (idx >= n8) return;
  const float4* s = (const float4*)w + (size_t)idx * 2;
  float4 v0 = s[0], v1 = s[1];
  U16x8 o;
  o.v[0]=f2bf(v0.x); o.v[1]=f2bf(v0.y); o.v[2]=f2bf(v0.z); o.v[3]=f2bf(v0.w);
  o.v[4]=f2bf(v1.x); o.v[5]=f2bf(v1.y); o.v[6]=f2bf(v1.z); o.v[7]=f2bf(v1.w);
  *(U16x8*)(wbf + (size_t)idx * 8) = o;
}

// ---------------- zero loss ----------------
__global__ void zero_k(float* __restrict__ loss) {
  if (threadIdx.x == 0) *loss = 0.f;
}

// ---------------- bf16 MFMA GEMM: G[m][n] = A[m][:] . W[n][:] + bih[n] + bhh[n] ----------------
__global__ void gemm_k(const u16* __restrict__ A, const u16* __restrict__ W,
                       const float* __restrict__ bih, const float* __restrict__ bhh,
                       u16* __restrict__ G) {
  __shared__ short Asm[64 * 40];
  __shared__ short Bsm[64 * 40];
  const int tid = threadIdx.x;
  const int m0 = blockIdx.x * 64, n0 = blockIdx.y * 64;
  const int wid = tid >> 6, lane = tid & 63;
  const int quad = lane >> 4, lr = lane & 15;
  const int wm = (wid >> 1) * 32, wn = (wid & 1) * 32;
  const int lrow = tid >> 2, lk = (tid & 3) * 8;
  floatx4 acc00 = {0,0,0,0}, acc01 = {0,0,0,0}, acc10 = {0,0,0,0}, acc11 = {0,0,0,0};
  for (int kt = 0; kt < 16; ++kt) {
    const int k0 = kt * 32;
    uint4 av = *(const uint4*)(A + (size_t)(m0 + lrow) * 512 + k0 + lk);
    uint4 bv = *(const uint4*)(W + (size_t)(n0 + lrow) * 512 + k0 + lk);
    __syncthreads();
    *(uint4*)&Asm[lrow * 40 + lk] = av;
    *(uint4*)&Bsm[lrow * 40 + lk] = bv;
    __syncthreads();
    short8v a0 = *(const short8v*)&Asm[(wm + lr) * 40 + quad * 8];
    short8v a1 = *(const short8v*)&Asm[(wm + 16 + lr) * 40 + quad * 8];
    short8v b0 = *(const short8v*)&Bsm[(wn + lr) * 40 + quad * 8];
    short8v b1 = *(const short8v*)&Bsm[(wn + 16 + lr) * 40 + quad * 8];
    acc00 = __builtin_amdgcn_mfma_f32_16x16x32_bf16(a0, b0, acc00, 0, 0, 0);
    acc01 = __builtin_amdgcn_mfma_f32_16x16x32_bf16(a0, b1, acc01, 0, 0, 0);
    acc10 = __builtin_amdgcn_mfma_f32_16x16x32_bf16(a1, b0, acc10, 0, 0, 0);
    acc11 = __builtin_amdgcn_mfma_f32_16x16x32_bf16(a1, b1, acc11, 0, 0, 0);
  }
  #pragma unroll
  for (int j = 0; j < 2; ++j) {
    const int n = n0 + wn + j * 16 + lr;
    const float bias = bih[n] + bhh[n];
    #pragma unroll
    for (int i = 0; i < 2; ++i) {
      const int mb = m0 + wm + i * 16 + quad * 4;
      floatx4 av = (i == 0) ? (j == 0 ? acc00 : acc01) : (j == 0 ? acc10 : acc11);
      #pragma unroll
      for (int rr = 0; rr < 4; ++rr) {
        G[(size_t)(mb + rr) * 2048 + n] = f2bf(av[rr] + bias);
      }
    }
  }
}

// ---------------- LSTM recurrence via MFMA, weights resident in VGPRs ----------------
// grid 32 = dir(2) x slice(4) x bg(4); 512 threads (8 waves).
// TAGGED-DATA sync: each exchanged h element is (bf16(h)<<16)|tag, tag =
// tag_base + step. Producer fire-and-forget stores (relaxed agent, NO drain,
// NO flag, NO end barrier); consumer polls its own 16B of h until all 4 tags
// match. Depth-2 parity slots; tags unique per step & layer; 0xAA poison
// never matches a tag. MFMA is 2-term (Whi+Wlo)*hhi — h residual term is
// 10-20x below bf16-G quantization error.
// G gates software-pipelined one step ahead; X staged in LDS, dumped every
// 8 steps as coalesced dwordx4 right after the next step's B1.
__launch_bounds__(512, 1)
__global__ void rec_k(const u16* __restrict__ G, const float* __restrict__ whh_l,
                      u32* __restrict__ Hbuf, int tag_base,
                      u16* __restrict__ Xbf, u32* __restrict__ Xu) {
  __shared__ u16 hhi_lds[16][264];   // [batch(8 real+8 zero)][k=256 pad 264]
  __shared__ float part[4 * 64 * 17]; // [type][jj][b pad17]
  __shared__ float clds[512];         // c state: [b][jj] = clds[tid]
  __shared__ u32 xst[8 * 512];        // X staging, 8 steps (u16 view for layer0)

  const int tid = threadIdx.x;
  const int dir = blockIdx.x >> 4;
  const int slice = (blockIdx.x >> 2) & 3;
  const int bg = blockIdx.x & 3;
  const int s64 = slice * 64;
  const int w = tid >> 6;
  const int lane = tid & 63;
  const int q = lane >> 4;      // quad
  const int lr = lane & 15;
  const int type = w >> 1;      // gate type for MFMA phase
  const int jjb = (w & 1) * 32; // hidden base within 64-slice

  const float* whh = whh_l + (size_t)dir * (1024 * 256);

  // ---- one-time: preload Whh slice into VGPR A-fragments (hi + lo residual) ----
  short8v Ahi[2][8], Alo[2][8];
  #pragma unroll
  for (int ti = 0; ti < 2; ++ti) {
    const float* wrow = whh + (size_t)(type * 256 + s64 + jjb + ti * 16 + lr) * 256;
    #pragma unroll
    for (int ks = 0; ks < 8; ++ks) {
      const float* pk = wrow + ks * 32 + q * 8;
      short8v hi, lo;
      #pragma unroll
      for (int j = 0; j < 8; ++j) {
        float v = pk[j];
        u16 hb = f2bf(v);
        hi[j] = (short)hb;
        lo[j] = (short)f2bf(v - bf2f(hb));
      }
      Ahi[ti][ks] = hi; Alo[ti][ks] = lo;
    }
  }
  for (int i = tid; i < 16 * 264; i += 512) ((u16*)hhi_lds)[i] = 0;
  clds[tid] = 0.f;

  u32* hb = Hbuf + (size_t)(dir * 4 + bg) * 4096;   // 2 parity * 2048 u32
  const int bu = w;       // updater: batch in group (0..7)
  const int ju = lane;    // updater: hidden in slice (0..63)
  const int cb_ = tid >> 6, k4 = (tid & 63) * 4;    // consumer (b, k-chunk)

  // preamble: load G[st=0]
  u16 gn0, gn1, gn2, gn3;
  {
    const int t0 = dir ? 511 : 0;
    const u16* gp = G + (size_t)(t0 * 32 + bg * 8 + bu) * 2048 + dir * 1024 + s64 + ju;
    gn0 = gp[0]; gn1 = gp[256]; gn2 = gp[512]; gn3 = gp[768];
  }
  __syncthreads();

  for (int st = 0; st < 512; ++st) {
    const int t = dir ? (511 - st) : st;
    // current step's gates (prefetched last iteration, already drained)
    const u16 gv0 = gn0, gv1 = gn1, gv2 = gn2, gv3 = gn3;
    if (st > 0) {
      // tagged-data poll: wait for this thread's 4 h values of step st
      const u32 want = (u32)(tag_base + st);
      const u64* src = (const u64*)(hb + (st & 1) * 2048);
      u64 p0, p1;
      int spin = 0;
      for (;;) {
        p0 = __hip_atomic_load(src + 2 * tid,     __ATOMIC_RELAXED, __HIP_MEMORY_SCOPE_AGENT);
        p1 = __hip_atomic_load(src + 2 * tid + 1, __ATOMIC_RELAXED, __HIP_MEMORY_SCOPE_AGENT);
        if (((u32)p0 & 0xffffu) == want && ((u32)(p0 >> 32) & 0xffffu) == want &&
            ((u32)p1 & 0xffffu) == want && ((u32)(p1 >> 32) & 0xffffu) == want) break;
        if (++spin > (1 << 20)) break;   // hang-avoidance only
      }
      // unpack hhi (high halves) -> LDS B-operand layout [b][k]
      u64 hiq = (u64)((u32)p0 >> 16) | ((u64)((u32)(p0 >> 32) >> 16) << 16)
              | ((u64)((u32)p1 >> 16) << 32) | ((u64)((u32)(p1 >> 32) >> 16) << 48);
      *(u64*)&hhi_lds[cb_][k4] = hiq;
    }
    __syncthreads();   // B1 (h ready in LDS; preamble G drained on st=0)
    // batched X dump for previous 8 steps (reads xst before anyone rewrites it;
    // writers of this step's slot only run after B2 -> barrier-ordered safe)
    if ((st & 7) == 0 && st > 0) {
      const int st0 = st - 8;
      if (Xbf) {
        const int slot = tid >> 6, r = tid & 63;
        const int b = r >> 3, f8 = (r & 7) * 8;
        const int tt = dir ? (511 - (st0 + slot)) : (st0 + slot);
        uint4 vv = *(const uint4*)&((u16*)xst)[slot * 512 + b * 64 + f8];
        *(uint4*)(Xbf + ((size_t)tt * 32 + bg * 8 + b) * 512 + dir * 256 + s64 + f8) = vv;
      } else {
        #pragma unroll
        for (int half = 0; half < 2; ++half) {
          const int seg = half * 512 + tid;
          const int slot = seg >> 7, rem = seg & 127;
          const int b = rem >> 4, f4 = (rem & 15) * 4;
          const int tt = dir ? (511 - (st0 + slot)) : (st0 + slot);
          uint4 vv = *(const uint4*)&xst[slot * 512 + b * 64 + f4];
          *(uint4*)(Xu + ((size_t)tt * 32 + bg * 8 + b) * 512 + dir * 256 + s64 + f4) = vv;
        }
      }
    }
    // prefetch NEXT step's G: hidden under MFMA, drained by B2's vmcnt(0)
    {
      const int stn = (st < 511) ? st + 1 : 511;
      const int tn = dir ? (511 - stn) : stn;
      const u16* gp = G + (size_t)(tn * 32 + bg * 8 + bu) * 2048 + dir * 1024 + s64 + ju;
      gn0 = gp[0]; gn1 = gp[256]; gn2 = gp[512]; gn3 = gp[768];
    }
    // MFMA phase: out[row][b] = W[row][:] . hhi[:][b]  (2-term hi/lo W split)
    floatx4 acc0 = {0,0,0,0}, acc1 = {0,0,0,0};
    #pragma unroll
    for (int ks = 0; ks < 8; ++ks) {
      short8v bhi = *(const short8v*)&hhi_lds[lr][ks * 32 + q * 8];
      acc0 = __builtin_amdgcn_mfma_f32_16x16x32_bf16(Ahi[0][ks], bhi, acc0, 0, 0, 0);
      acc1 = __builtin_amdgcn_mfma_f32_16x16x32_bf16(Ahi[1][ks], bhi, acc1, 0, 0, 0);
      acc0 = __builtin_amdgcn_mfma_f32_16x16x32_bf16(Alo[0][ks], bhi, acc0, 0, 0, 0);
      acc1 = __builtin_amdgcn_mfma_f32_16x16x32_bf16(Alo[1][ks], bhi, acc1, 0, 0, 0);
    }
    // C layout: col(b)=lane&15, row(jj)=quad*4+reg
    #pragma unroll
    for (int reg = 0; reg < 4; ++reg) {
      part[(type * 64 + jjb +      q * 4 + reg) * 17 + lr] = acc0[reg];
      part[(type * 64 + jjb + 16 + q * 4 + reg) * 17 + lr] = acc1[reg];
    }
    __syncthreads();   // B2 (part visible; G prefetch drained)
    // updater phase: all 512 threads, one (b,jj) each
    float si = bf2f(gv0) + part[(0 * 64 + ju) * 17 + bu];
    float sf = bf2f(gv1) + part[(1 * 64 + ju) * 17 + bu];
    float sg = bf2f(gv2) + part[(2 * 64 + ju) * 17 + bu];
    float so = bf2f(gv3) + part[(3 * 64 + ju) * 17 + bu];
    float cold = clds[tid];
    float ig = sigf(si), fg = sigf(sf), gg = tanh_f(sg), og = sigf(so);
    float cn = fg * cold + ig * gg;
    float hn = og * tanh_f(cn);
    clds[tid] = cn;
    u16 hhi = f2bf(hn);
    // fire-and-forget tagged h store: data arrival IS the signal
    u32 hv = ((u32)hhi << 16) | (u32)((tag_base + st + 1) & 0xffff);
    __hip_atomic_store(hb + ((st + 1) & 1) * 2048 + bu * 256 + s64 + ju, hv,
                       __ATOMIC_RELAXED, __HIP_MEMORY_SCOPE_AGENT);
    // stage X in LDS (dumped every 8 steps, off the signal path)
    if (Xbf) ((u16*)xst)[(st & 7) * 512 + tid] = hhi;
    else {
      u16 hlo = f2bf(hn - bf2f(hhi));
      xst[(st & 7) * 512 + tid] = ((u32)hhi << 16) | hlo;
    }
    // NO end-of-step barrier, NO store drain, NO flag.
  }
  // epilogue: dump last 8 staged steps
  __syncthreads();
  {
    const int st0 = 504;
    if (Xbf) {
      const int slot = tid >> 6, r = tid & 63;
      const int b = r >> 3, f8 = (r & 7) * 8;
      const int tt = dir ? (511 - (st0 + slot)) : (st0 + slot);
      uint4 vv = *(const uint4*)&((u16*)xst)[slot * 512 + b * 64 + f8];
      *(uint4*)(Xbf + ((size_t)tt * 32 + bg * 8 + b) * 512 + dir * 256 + s64 + f8) = vv;
    } else {
      #pragma unroll
      for (int half = 0; half < 2; ++half) {
        const int seg = half * 512 + tid;
        const int slot = seg >> 7, rem = seg & 127;
        const int b = rem >> 4, f4 = (rem & 15) * 4;
        const int tt = dir ? (511 - (st0 + slot)) : (st0 + slot);
        uint4 vv = *(const uint4*)&xst[slot * 512 + b * 64 + f4];
        *(uint4*)(Xu + ((size_t)tt * 32 + bg * 8 + b) * 512 + dir * 256 + s64 + f4) = vv;
      }
    }
  }
}

// ---------------- LayerNorm + classifier head; logits -> d_out+1 ----------------
// X2u: packed (bf16hi<<16|bf16lo) per element; decode = bf2f(hi)+bf2f(lo)
__global__ void head_k(const u32* __restrict__ X2u, const float* __restrict__ gamma,
                       const float* __restrict__ beta, const float* __restrict__ cw,
                       const float* __restrict__ cb, float* __restrict__ out) {
  __shared__ float red[9][64];
  const int m = blockIdx.x, lane = threadIdx.x;
  const int s = m >> 5, b = m & 31;
  const uint4* xp = (const uint4*)(X2u + (size_t)m * 512) + lane * 2;
  uint4 a0 = xp[0], a1 = xp[1];
  float x[8];
  x[0] = decode_hl(a0.x); x[1] = decode_hl(a0.y);
  x[2] = decode_hl(a0.z); x[3] = decode_hl(a0.w);
  x[4] = decode_hl(a1.x); x[5] = decode_hl(a1.y);
  x[6] = decode_hl(a1.z); x[7] = decode_hl(a1.w);
  float sm = 0.f, sq = 0.f;
  #pragma unroll
  for (int i = 0; i < 8; ++i) { sm += x[i]; sq += x[i] * x[i]; }
  #pragma unroll
  for (int off = 32; off > 0; off >>= 1) {
    sm += __shfl_xor(sm, off, 64);
    sq += __shfl_xor(sq, off, 64);
  }
  const float mu = sm * (1.0f / 512.0f);
  const float var = sq * (1.0f / 512.0f) - mu * mu;
  const float rs = rsqrtf(var + 1e-5f);
  const float4* gp = (const float4*)gamma + lane * 2;
  const float4* bp = (const float4*)beta + lane * 2;
  float4 g0 = gp[0], g1 = gp[1], be0 = bp[0], be1 = bp[1];
  float nv[8];
  nv[0] = (x[0] - mu) * rs * g0.x + be0.x;
  nv[1] = (x[1] - mu) * rs * g0.y + be0.y;
  nv[2] = (x[2] - mu) * rs * g0.z + be0.z;
  nv[3] = (x[3] - mu) * rs * g0.w + be0.w;
  nv[4] = (x[4] - mu) * rs * g1.x + be1.x;
  nv[5] = (x[5] - mu) * rs * g1.y + be1.y;
  nv[6] = (x[6] - mu) * rs * g1.z + be1.z;
  nv[7] = (x[7] - mu) * rs * g1.w + be1.w;
  #pragma unroll
  for (int c = 0; c < 9; ++c) {
    const float4* wp = (const float4*)(cw + (size_t)c * 512) + lane * 2;
    float4 w0 = wp[0], w1 = wp[1];
    red[c][lane] = nv[0]*w0.x + nv[1]*w0.y + nv[2]*w0.z + nv[3]*w0.w
                 + nv[4]*w1.x + nv[5]*w1.y + nv[6]*w1.z + nv[7]*w1.w;
  }
  __syncthreads();
  if (lane < 9) {
    float t = 0.f;
    for (int i = 0; i < 64; ++i) t += red[lane][i];
    out[1 + ((size_t)b * 512 + s) * 9 + lane] = t + cb[lane];
  }
}

// ---------------- CRF NLL: one wave per batch element ----------------
__global__ void crf_k(const float* __restrict__ logits, const int* __restrict__ labels,
                      const int* __restrict__ lens, const float* __restrict__ tr,
                      float* __restrict__ loss) {
  const int b = blockIdx.x, lane = threadIdx.x;
  const int len = lens[b];
  float trj[9];
  #pragma unroll
  for (int i = 0; i < 9; ++i) trj[i] = 0.f;
  if (lane < 9) {
    #pragma unroll
    for (int i = 0; i < 9; ++i) trj[i] = tr[i * 11 + lane];
  }
  float alpha = -1e30f;
  if (lane < 9) alpha = tr[9 * 11 + lane] + logits[(size_t)b * 512 * 9 + lane];
  for (int t = 1; t < len; ++t) {
    float e = (lane < 9) ? logits[((size_t)b * 512 + t) * 9 + lane] : 0.f;
    float v[9];
    float mx = -1e30f;
    #pragma unroll
    for (int i = 0; i < 9; ++i) {
      v[i] = __shfl(alpha, i, 64) + trj[i];
      mx = fmaxf(mx, v[i]);
    }
    float ss = 0.f;
    #pragma unroll
    for (int i = 0; i < 9; ++i) ss += __expf(v[i] - mx);
    float na = mx + __logf(ss) + e;
    if (lane < 9) alpha = na;
  }
  float fin = (lane < 9) ? alpha + tr[lane * 11 + 10] : -1e30f;
  float mx = fin;
  #pragma unroll
  for (int off = 8; off > 0; off >>= 1) mx = fmaxf(mx, __shfl_xor(mx, off, 64));
  float es = (lane < 9) ? __expf(fin - mx) : 0.f;
  #pragma unroll
  for (int off = 8; off > 0; off >>= 1) es += __shfl_xor(es, off, 64);
  const float logZ = mx + __logf(es);
  float emit = 0.f, ts = 0.f;
  for (int t = lane; t < len; t += 64) {
    int y = labels[b * 512 + t];
    emit += logits[((size_t)b * 512 + t) * 9 + y];
  }
  for (int t = 1 + lane; t < len; t += 64) {
    int y0 = labels[b * 512 + t - 1], y1 = labels[b * 512 + t];
    ts += tr[y0 * 11 + y1];
  }
  #pragma unroll
  for (int off = 32; off > 0; off >>= 1) {
    emit += __shfl_xor(emit, off, 64);
    ts += __shfl_xor(ts, off, 64);
  }
  if (lane == 0) {
    int y0 = labels[b * 512], yl = labels[b * 512 + len - 1];
    float gold = emit + ts + tr[9 * 11 + y0] + tr[yl * 11 + 10];
    atomicAdd(loss, (logZ - gold) * (1.0f / 32.0f));
  }
}

extern "C" void kernel_launch(void* const* d_in, const int* in_sizes, int n_in,
                              void* d_out, int out_size, void* d_ws, size_t ws_size,
                              hipStream_t stream) {
  const int* ids = (const int*)d_in[0];
  const int* amask = (const int*)d_in[1];
  const int* lens = (const int*)d_in[2];
  const int* labels = (const int*)d_in[3];
  const float* emb = (const float*)d_in[4];
  const float* w_ih = (const float*)d_in[5];
  const float* w_hh = (const float*)d_in[6];
  const float* b_ih = (const float*)d_in[7];
  const float* b_hh = (const float*)d_in[8];
  const float* gamma = (const float*)d_in[9];
  const float* beta = (const float*)d_in[10];
  const float* cw = (const float*)d_in[11];
  const float* cb = (const float*)d_in[12];
  const float* tr = (const float*)d_in[13];
  (void)in_sizes; (void)n_in; (void)out_size;

  if (ws_size < WS_NEEDED) return;  // workspace too small -> clean failure

  char* p = (char*)d_ws;
  u16* X0 = (u16*)p;      p += (size_t)16384 * 512 * 2;        // 16.78 MB
  u16* Wbf = (u16*)p;     p += (size_t)2 * 2 * 1024 * 512 * 2; // 4.19 MB
  u16* G = (u16*)p;       p += (size_t)16384 * 2048 * 2;       // 67.1 MB
  u16* X1 = (u16*)p;      p += (size_t)16384 * 512 * 2;        // 16.78 MB
  u32* X2u = (u32*)p;     p += (size_t)16384 * 512 * 4;        // 33.55 MB
  u32* Hb = (u32*)p;      p += (size_t)32768 * 4;              // 128 KB
  float* out = (float*)d_out;

  prep_k<<<16384, 64, 0, stream>>>(ids, amask, emb, X0);
  conv_k<<<1024, 256, 0, stream>>>(w_ih, Wbf, 262144);
  zero_k<<<1, 64, 0, stream>>>(out);
  // Layer 0 (tags 1..512)
  gemm_k<<<dim3(256, 32), 256, 0, stream>>>(X0, Wbf, b_ih, b_hh, G);
  rec_k<<<32, 512, 0, stream>>>(G, w_hh, Hb, 0, X1, nullptr);
  // Layer 1 (tags 1025..1536 — never aliases layer 0 or 0xAAAA poison)
  gemm_k<<<dim3(256, 32), 256, 0, stream>>>(X1, Wbf + 2 * 1024 * 512,
                                            b_ih + 2048, b_hh + 2048, G);
  rec_k<<<32, 512, 0, stream>>>(G, w_hh + 2 * 1024 * 256, Hb, 1024,
                                nullptr, X2u);
  // Head + CRF
  head_k<<<16384, 64, 0, stream>>>(X2u, gamma, beta, cw, cb, out);
  crf_k<<<32, 64, 0, stream>>>(out + 1, labels, lens, tr, out);
}